// Round 1
// baseline (3767.422 us; speedup 1.0000x reference)
//
#include <hip/hip_runtime.h>
#include <cmath>

namespace {
constexpr int B_ = 16, T_ = 512, P_ = 256, E_ = 128, NB_ = 4, K_ = 4, NOFF = 9;
}

// One block per batch element. Ring state (P x E f32 = 128 KiB) lives in LDS.
// 256 threads: e = tid & 127 (output column), half = tid >> 7 (k-split for matvec).
// 1 block/CU (LDS-bound) -> 1 wave/SIMD -> VGPR budget 512; W_p slice cached in regs.
__global__ __launch_bounds__(256, 1)
void swarm_ring_kernel(const float* __restrict__ x,            // (B,T,8)
                       const float* __restrict__ W_in,         // (8,E)
                       const float* __restrict__ b_in,         // (E)
                       const float* __restrict__ W_out,        // (E,8)
                       const float* __restrict__ b_out,        // (8)
                       const float* __restrict__ W_p,          // (E,E)
                       const float* __restrict__ b_p,          // (E)
                       const float* __restrict__ ptr_dest,     // (NB,P)
                       const float* __restrict__ jump_W,       // (NB,E)
                       const float* __restrict__ jump_b,       // (NB)
                       const float* __restrict__ ctx_strength, // (NB)
                       const float* __restrict__ phase_bias,   // (NB,E)
                       const float* __restrict__ pointer_init, // (NB,B)
                       float* __restrict__ out)                // (B,T,8)
{
    __shared__ float ring[P_ * E_];       // 128 KiB
    __shared__ float s_lds[E_];
    __shared__ float red[256 + 32];       // matvec partials + [256..279] reduce slots

    const int tid  = threadIdx.x;
    const int b    = blockIdx.x;
    const int e    = tid & (E_ - 1);
    const int half = tid >> 7;

    // zero ring state (reference starts from zeros)
    for (int k = tid; k < P_ * E_; k += 256) ring[k] = 0.0f;

    // cache W_p slice in registers: wp[kk] = W_p[half*64+kk][e]
    float wp[64];
    #pragma unroll
    for (int kk = 0; kk < 64; ++kk)
        wp[kk] = W_p[(half * 64 + kk) * E_ + e];

    const float bin_r = b_in[e];
    const float bp_r  = b_p[e];
    float win_r[8];
    #pragma unroll
    for (int k = 0; k < 8; ++k) win_r[k] = W_in[k * E_ + e];
    float wout_r[8];
    #pragma unroll
    for (int m = 0; m < 8; ++m) wout_r[m] = W_out[e * 8 + m];

    float pb_r[NB_], jw_r[NB_], sigc[NB_], jb_r[NB_], hid[NB_], ptrv[NB_];
    #pragma unroll
    for (int i = 0; i < NB_; ++i) {
        pb_r[i] = 0.1f * phase_bias[i * E_ + e];
        jw_r[i] = jump_W[i * E_ + e];
        sigc[i] = 1.0f / (1.0f + expf(-ctx_strength[i]));
        jb_r[i] = jump_b[i];
        hid[i]  = 0.0f;
        ptrv[i] = pointer_init[i * B_ + b];
    }
    const float bout_r = (tid < 8) ? b_out[tid] : 0.0f;

    const float* xb = x + (size_t)b * T_ * 8;
    float xt[8];
    #pragma unroll
    for (int k = 0; k < 8; ++k) xt[k] = xb[k];

    __syncthreads();

    for (int t = 0; t < T_; ++t) {
        // prefetch next x_t (latency hidden under this timestep's work)
        float xtn[8];
        #pragma unroll
        for (int k = 0; k < 8; ++k) xtn[k] = 0.0f;
        if (t + 1 < T_) {
            #pragma unroll
            for (int k = 0; k < 8; ++k) xtn[k] = xb[(t + 1) * 8 + k];
        }
        // prefetch jump targets (depend only on carry pointers)
        float jt[NB_];
        #pragma unroll
        for (int i = 0; i < NB_; ++i) {
            int cur = (int)ptrv[i];                 // astype(int32), ptr >= 0
            cur = cur < 0 ? 0 : (cur > P_ - 1 ? P_ - 1 : cur);
            jt[i] = ptr_dest[i * P_ + cur];
        }
        // inp = x_t @ W_in + b_in (shared across bots)
        float inp = bin_r;
        #pragma unroll
        for (int k = 0; k < 8; ++k) inp = fmaf(xt[k], win_r[k], inp);

        float ssum = 0.0f;
        float sv[NB_];

        #pragma unroll
        for (int i = 0; i < NB_; ++i) {
            const float ptr = ptrv[i];
            int base = (int)floorf(ptr);
            base = base < 0 ? 0 : (base > P_ - 1 ? P_ - 1 : base);

            int   idx[NOFF];
            float nbv[NOFF];
            #pragma unroll
            for (int o = 0; o < NOFF; ++o) {        // issue gathers first
                idx[o] = (base + o - K_ + P_) & (P_ - 1);
                nbv[o] = ring[idx[o] * E_ + e];
            }
            // softmax weights (computed while gather latency drains)
            float w[NOFF];
            float mx = -3.402823466e38f;
            #pragma unroll
            for (int o = 0; o < NOFF; ++o) {
                float v = (float)idx[o] - ptr + 128.0f;      // delta = floormod(v,256)-128
                v = v - 256.0f * floorf(v * (1.0f / 256.0f));
                float d = v - 128.0f;
                w[o] = -(d * d) * 0.125f;                    // -delta^2 / TEMP
                mx = fmaxf(mx, w[o]);
            }
            float sum = 0.0f;
            #pragma unroll
            for (int o = 0; o < NOFF; ++o) { w[o] = expf(w[o] - mx); sum += w[o]; }
            #pragma unroll
            for (int o = 0; o < NOFF; ++o) w[o] /= sum;

            float ctx = 0.0f;
            #pragma unroll
            for (int o = 0; o < NOFF; ++o) ctx = fmaf(w[o], nbv[o], ctx);

            const float s1v = tanhf(inp + sigc[i] * ctx + pb_r[i] + hid[i]);
            if (half == 0) s_lds[e] = s1v;
            __syncthreads();                                  // S1: s ready

            // matvec partial: sum_{k in half's 64} s[k] * W_p[k][e]
            float acc = 0.0f;
            const float4* s4p = (const float4*)(s_lds + half * 64);
            #pragma unroll
            for (int k4 = 0; k4 < 16; ++k4) {
                float4 s4 = s4p[k4];                          // wave-uniform b128 broadcast
                acc = fmaf(s4.x, wp[4 * k4 + 0], acc);
                acc = fmaf(s4.y, wp[4 * k4 + 1], acc);
                acc = fmaf(s4.z, wp[4 * k4 + 2], acc);
                acc = fmaf(s4.w, wp[4 * k4 + 3], acc);
            }
            red[tid] = acc;
            __syncthreads();                                  // S2: partials ready

            const float s2 = tanhf(red[e] + red[e + 128] + bp_r);
            hid[i] = s2;
            ssum  += s2;
            sv[i]  = s2;

            // ring scatter-add, offsets split across halves (disjoint rows, no atomics)
            if (half == 0) {
                float tmp[5];
                #pragma unroll
                for (int o = 0; o < 5; ++o) tmp[o] = ring[idx[o] * E_ + e];
                #pragma unroll
                for (int o = 0; o < 5; ++o) ring[idx[o] * E_ + e] = tmp[o] + w[o] * s2;
            } else {
                float tmp[4];
                #pragma unroll
                for (int o = 0; o < 4; ++o) tmp[o] = ring[idx[o + 5] * E_ + e];
                #pragma unroll
                for (int o = 0; o < 4; ++o) ring[idx[o + 5] * E_ + e] = tmp[o] + w[o + 5] * s2;
            }
            __syncthreads();                                  // S3: ring updated
        }

        // deferred reductions: 8 output dots + 4 jump dots, butterfly within waves 0/1
        if (tid < 128) {
            float v[12];
            #pragma unroll
            for (int m = 0; m < 8; ++m) v[m] = ssum * wout_r[m];
            #pragma unroll
            for (int i = 0; i < NB_; ++i) v[8 + i] = sv[i] * jw_r[i];
            #pragma unroll
            for (int m = 0; m < 12; ++m) {
                float vv = v[m];
                #pragma unroll
                for (int off = 32; off > 0; off >>= 1) vv += __shfl_xor(vv, off);
                v[m] = vv;
            }
            if ((tid & 63) == 0) {
                const int w2 = tid >> 6;                      // 0 or 1
                #pragma unroll
                for (int m = 0; m < 12; ++m) red[256 + w2 * 12 + m] = v[m];
            }
        }
        __syncthreads();                                      // S13: partials visible

        // all threads update pointers redundantly in registers (no extra barrier)
        #pragma unroll
        for (int i = 0; i < NB_; ++i) {
            const float z = red[256 + 8 + i] + red[256 + 12 + 8 + i] + jb_r[i];
            float np;
            if (z > 0.0f) {                                   // sigmoid(z) > 0.5
                np = jt[i];
            } else {
                np = ptrv[i] + 1.0f;
                if (np >= 256.0f) np -= 256.0f;               // (ptr+1) % P
            }
            ptrv[i] = np;
        }
        if (tid < 8) {
            const float ov = 0.25f * (red[256 + tid] + red[256 + 12 + tid]) + bout_r;
            out[((size_t)b * T_ + t) * 8 + tid] = ov;
        }

        #pragma unroll
        for (int k = 0; k < 8; ++k) xt[k] = xtn[k];
    }
}

extern "C" void kernel_launch(void* const* d_in, const int* in_sizes, int n_in,
                              void* d_out, int out_size, void* d_ws, size_t ws_size,
                              hipStream_t stream) {
    (void)in_sizes; (void)n_in; (void)out_size; (void)d_ws; (void)ws_size;
    swarm_ring_kernel<<<dim3(B_), dim3(256), 0, stream>>>(
        (const float*)d_in[0],  (const float*)d_in[1],  (const float*)d_in[2],
        (const float*)d_in[3],  (const float*)d_in[4],  (const float*)d_in[5],
        (const float*)d_in[6],  (const float*)d_in[7],  (const float*)d_in[8],
        (const float*)d_in[9],  (const float*)d_in[10], (const float*)d_in[11],
        (const float*)d_in[12], (float*)d_out);
}

// Round 2
// 2610.416 us; speedup vs baseline: 1.4432x; 1.4432x over previous
//
#include <hip/hip_runtime.h>
#include <cmath>

namespace {
constexpr int B_ = 16, T_ = 512, P_ = 256, E_ = 128, NB_ = 4, K_ = 4, NOFF = 9;

__device__ __forceinline__ float rcpf(float x) {
#if __has_builtin(__builtin_amdgcn_rcpf)
    return __builtin_amdgcn_rcpf(x);
#else
    return 1.0f / x;
#endif
}
__device__ __forceinline__ float fast_tanh(float x) {
    float a = fabsf(x);
    float t = __expf(-2.0f * a);
    float r = 1.0f - 2.0f * t * rcpf(1.0f + t);
    return copysignf(r, x);
}
}

// 1 block / batch element; ring (P x E f32 = 128 KiB) in LDS.
// Thread map: wave = tid>>6 owns e in [wave*32, wave*32+32); lanes l and l+32
// share e (khalf = lane>>5 is the k-split of the W_p matvec -> combine via
// __shfl_xor(32), no barrier). 5 barriers/step: 4 matvec broadcasts + 1 end.
__global__ __launch_bounds__(256, 1)
void swarm_ring_kernel(const float* __restrict__ x,            // (B,T,8)
                       const float* __restrict__ W_in,         // (8,E)
                       const float* __restrict__ b_in,         // (E)
                       const float* __restrict__ W_out,        // (E,8)
                       const float* __restrict__ b_out,        // (8)
                       const float* __restrict__ W_p,          // (E,E)
                       const float* __restrict__ b_p,          // (E)
                       const float* __restrict__ ptr_dest,     // (NB,P)
                       const float* __restrict__ jump_W,       // (NB,E)
                       const float* __restrict__ jump_b,       // (NB)
                       const float* __restrict__ ctx_strength, // (NB)
                       const float* __restrict__ phase_bias,   // (NB,E)
                       const float* __restrict__ pointer_init, // (NB,B)
                       float* __restrict__ out)                // (B,T,8)
{
    __shared__ alignas(16) float ring[P_ * E_];   // 128 KiB
    __shared__ alignas(16) float s_buf[2 * E_];   // double-buffered s broadcast
    __shared__ float red[64];                     // [wave*16 + q], q<12

    const int tid   = threadIdx.x;
    const int b     = blockIdx.x;
    const int wave  = tid >> 6;
    const int lane  = tid & 63;
    const int khalf = lane >> 5;
    const int e     = (wave << 5) | (lane & 31);

    for (int k4 = tid; k4 < P_ * E_ / 4; k4 += 256)
        ((float4*)ring)[k4] = make_float4(0.f, 0.f, 0.f, 0.f);

    float wp[64];                                  // W_p[khalf*64+kk][e]
    #pragma unroll
    for (int kk = 0; kk < 64; ++kk) wp[kk] = W_p[(khalf * 64 + kk) * E_ + e];

    const float bin_r = b_in[e];
    const float bp_r  = b_p[e];
    float win_r[8], wout_r[8];
    #pragma unroll
    for (int k = 0; k < 8; ++k) win_r[k] = W_in[k * E_ + e];
    #pragma unroll
    for (int m = 0; m < 8; ++m) wout_r[m] = W_out[e * 8 + m];

    float pb_r[NB_], jw_r[NB_], sigc[NB_], jb_r[NB_], hid[NB_], ptrv[NB_];
    #pragma unroll
    for (int i = 0; i < NB_; ++i) {
        pb_r[i] = 0.1f * phase_bias[i * E_ + e];
        jw_r[i] = jump_W[i * E_ + e];
        sigc[i] = 1.0f / (1.0f + __expf(-ctx_strength[i]));
        jb_r[i] = jump_b[i];
        hid[i]  = 0.0f;
        ptrv[i] = pointer_init[i * B_ + b];
    }
    const float bout_r = (tid < 8) ? b_out[tid] : 0.0f;

    const float* xb = x + (size_t)b * T_ * 8;
    float xt[8];
    {
        float4 a0 = ((const float4*)xb)[0], a1 = ((const float4*)xb)[1];
        xt[0]=a0.x; xt[1]=a0.y; xt[2]=a0.z; xt[3]=a0.w;
        xt[4]=a1.x; xt[5]=a1.y; xt[6]=a1.z; xt[7]=a1.w;
    }

    // softmax taper constants: Cw_k = exp(-k^2/8), D_k = exp(-k^2/4)
    const float Cw1 = 0.8824969f, Cw2 = 0.60653066f, Cw3 = 0.32465247f, Cw4 = 0.13533528f;
    const float Dw1 = 0.7788008f, Dw2 = 0.36787944f, Dw3 = 0.105399225f, Dw4 = 0.018315639f;

    __syncthreads();

    for (int t = 0; t < T_; ++t) {
        // ---- step start: geometry, weights, jump-target prefetch (all from carry ptrs)
        int   baseA[NB_];
        float fA[NB_], psinv[NB_], jt[NB_], wgt[NB_][NOFF];
        #pragma unroll
        for (int i = 0; i < NB_; ++i) {
            const float p = ptrv[i];
            int base = (int)p;                       // p in [0,256): trunc == floor == clip
            baseA[i] = base;
            jt[i] = ptr_dest[i * P_ + base];         // cur == base (prefetch, used at step end)
            const float f = p - (float)base;
            fA[i] = f;
            // w_o ∝ Cw_{|o-4|} * r^(o-4),  r = exp(f/4)  (common factor drops in softmax)
            const float r  = __expf(0.25f * f);
            const float r2 = r * r, r3 = r2 * r, r4 = r2 * r2;
            const float ri = rcpf(r), ri2 = ri * ri, ri3 = ri2 * ri, ri4 = ri2 * ri2;
            float p0 = Cw4*ri4, p1 = Cw3*ri3, p2 = Cw2*ri2, p3 = Cw1*ri, p4 = 1.0f,
                  p5 = Cw1*r,  p6 = Cw2*r2,  p7 = Cw3*r3,  p8 = Cw4*r4;
            const float sum = ((p0+p1)+(p2+p3)) + ((p4+p5)+(p6+p7)) + p8;
            const float inv = rcpf(sum);
            psinv[i] = inv;
            wgt[i][0]=p0*inv; wgt[i][1]=p1*inv; wgt[i][2]=p2*inv; wgt[i][3]=p3*inv;
            wgt[i][4]=p4*inv; wgt[i][5]=p5*inv; wgt[i][6]=p6*inv; wgt[i][7]=p7*inv;
            wgt[i][8]=p8*inv;
        }

        // ---- all 4 bots' gathers from step-start ring (no scatter has landed yet)
        float g[NB_][NOFF];
        #pragma unroll
        for (int i = 0; i < NB_; ++i)
            #pragma unroll
            for (int o = 0; o < NOFF; ++o)
                g[i][o] = ring[(((baseA[i] + o - K_) & (P_ - 1)) * E_) + e];

        float ctxp[NB_];
        #pragma unroll
        for (int i = 0; i < NB_; ++i) {
            float c = 0.f;
            #pragma unroll
            for (int o = 0; o < NOFF; ++o) c = fmaf(wgt[i][o], g[i][o], c);
            ctxp[i] = c;
        }

        // ---- cross-bot correction coefficients: coef[j][i] = sum_rows w_i * w_j
        float coefm[NB_][NB_];
        #pragma unroll
        for (int j = 1; j < NB_; ++j) {
            #pragma unroll
            for (int i = 0; i < j; ++i) {
                int dd = ((baseA[j] - baseA[i] + 128) & 255) - 128;
                float c = 0.f;
                if (dd >= -8 && dd <= 8) {
                    const float A = (float)dd - fA[i];
                    const float s  = __expf(-0.25f * (A - fA[j]));
                    const float G  = __expf(0.125f * (fA[i] * fA[i] - A * A));
                    const float s2p = s * s, s3p = s2p * s, s4p = s2p * s2p;
                    const float si = rcpf(s), si2 = si * si, si3 = si2 * si, si4 = si2 * si2;
                    float acc = 0.f;
                    acc += (dd >= 0 && dd <= 8) ? Dw4 * si4 : 0.f;   // o=0, u=-4
                    acc += (dd >= -1 && dd <= 7) ? Dw3 * si3 : 0.f;  // o=1
                    acc += (dd >= -2 && dd <= 6) ? Dw2 * si2 : 0.f;  // o=2
                    acc += (dd >= -3 && dd <= 5) ? Dw1 * si  : 0.f;  // o=3
                    acc += (dd >= -4 && dd <= 4) ? 1.0f      : 0.f;  // o=4, u=0
                    acc += (dd >= -5 && dd <= 3) ? Dw1 * s   : 0.f;  // o=5
                    acc += (dd >= -6 && dd <= 2) ? Dw2 * s2p : 0.f;  // o=6
                    acc += (dd >= -7 && dd <= 1) ? Dw3 * s3p : 0.f;  // o=7
                    acc += (dd >= -8 && dd <= 0) ? Dw4 * s4p : 0.f;  // o=8, u=4
                    c = psinv[i] * psinv[j] * G * acc;
                }
                coefm[j][i] = c;
            }
        }

        // inp = x_t @ W_in + b_in
        float inp = bin_r;
        #pragma unroll
        for (int k = 0; k < 8; ++k) inp = fmaf(xt[k], win_r[k], inp);

        // prefetch next x_t
        float xtn[8];
        if (t + 1 < T_) {
            float4 a0 = ((const float4*)(xb + (t + 1) * 8))[0];
            float4 a1 = ((const float4*)(xb + (t + 1) * 8))[1];
            xtn[0]=a0.x; xtn[1]=a0.y; xtn[2]=a0.z; xtn[3]=a0.w;
            xtn[4]=a1.x; xtn[5]=a1.y; xtn[6]=a1.z; xtn[7]=a1.w;
        } else {
            #pragma unroll
            for (int k = 0; k < 8; ++k) xtn[k] = 0.f;
        }

        // ---- serial bot chain
        float sv[NB_];
        #pragma unroll
        for (int j = 0; j < NB_; ++j) {
            float ctx = ctxp[j];
            #pragma unroll
            for (int i = 0; i < j; ++i) ctx = fmaf(coefm[j][i], sv[i], ctx);
            const float s1 = fast_tanh(fmaf(sigc[j], ctx, inp + pb_r[j] + hid[j]));
            if (khalf == 0) s_buf[(j & 1) * E_ + e] = s1;
            __syncthreads();                              // s broadcast ready

            const float4* sp = (const float4*)(s_buf + (j & 1) * E_ + khalf * 64);
            float acc = 0.f;
            #pragma unroll
            for (int k4 = 0; k4 < 16; ++k4) {
                float4 s4 = sp[k4];                       // 2-addr broadcast (free)
                acc = fmaf(s4.x, wp[4 * k4 + 0], acc);
                acc = fmaf(s4.y, wp[4 * k4 + 1], acc);
                acc = fmaf(s4.z, wp[4 * k4 + 2], acc);
                acc = fmaf(s4.w, wp[4 * k4 + 3], acc);
            }
            acc += __shfl_xor(acc, 32);                   // combine k-split in-wave
            const float s2 = fast_tanh(acc + bp_r);
            sv[j] = s2; hid[j] = s2;

            // scatter-add, owned by absolute row parity (race-free across bots)
            const int o0 = (baseA[j] ^ khalf) & 1;        // o parity with (row&1)==khalf
            #pragma unroll
            for (int u = 0; u < 4; ++u) {
                const float wv = o0 ? wgt[j][2 * u + 1] : wgt[j][2 * u];
                const int r = (baseA[j] + 2 * u + o0 - K_) & (P_ - 1);
                ring[r * E_ + e] += wv * s2;
            }
            if (o0 == 0) {
                const int r = (baseA[j] + 8 - K_) & (P_ - 1);
                ring[r * E_ + e] += wgt[j][8] * s2;
            }
            // no barrier: next bot uses step-start gathers + coef corrections
        }

        // ---- deferred reductions: 8 out dots + 4 jump dots
        {
            const float ssum = (sv[0] + sv[1]) + (sv[2] + sv[3]);
            float v[12];
            #pragma unroll
            for (int m = 0; m < 8; ++m) v[m] = ssum * wout_r[m];
            #pragma unroll
            for (int i = 0; i < NB_; ++i) v[8 + i] = sv[i] * jw_r[i];
            #pragma unroll
            for (int m = 0; m < 12; ++m) {                // 5 levels: sum over 32-lane half
                float vv = v[m];
                vv += __shfl_xor(vv, 1);
                vv += __shfl_xor(vv, 2);
                vv += __shfl_xor(vv, 4);
                vv += __shfl_xor(vv, 8);
                vv += __shfl_xor(vv, 16);
                v[m] = vv;
            }
            if (lane == 0) {
                #pragma unroll
                for (int m = 0; m < 12; ++m) red[wave * 16 + m] = v[m];
            }
        }
        __syncthreads();                                  // end-of-step: scatters + partials

        // pointer updates (redundant in all threads; z>0 <=> sigmoid>0.5)
        #pragma unroll
        for (int i = 0; i < NB_; ++i) {
            const float z = ((red[8 + i] + red[16 + 8 + i]) +
                             (red[32 + 8 + i] + red[48 + 8 + i])) + jb_r[i];
            float np;
            if (z > 0.0f) np = jt[i];
            else { np = ptrv[i] + 1.0f; if (np >= 256.0f) np -= 256.0f; }
            ptrv[i] = np;
        }
        if (tid < 8) {
            const float ov = 0.25f * ((red[tid] + red[16 + tid]) +
                                      (red[32 + tid] + red[48 + tid])) + bout_r;
            out[((size_t)b * T_ + t) * 8 + tid] = ov;
        }

        #pragma unroll
        for (int k = 0; k < 8; ++k) xt[k] = xtn[k];
    }
}

extern "C" void kernel_launch(void* const* d_in, const int* in_sizes, int n_in,
                              void* d_out, int out_size, void* d_ws, size_t ws_size,
                              hipStream_t stream) {
    (void)in_sizes; (void)n_in; (void)out_size; (void)d_ws; (void)ws_size;
    swarm_ring_kernel<<<dim3(B_), dim3(256), 0, stream>>>(
        (const float*)d_in[0],  (const float*)d_in[1],  (const float*)d_in[2],
        (const float*)d_in[3],  (const float*)d_in[4],  (const float*)d_in[5],
        (const float*)d_in[6],  (const float*)d_in[7],  (const float*)d_in[8],
        (const float*)d_in[9],  (const float*)d_in[10], (const float*)d_in[11],
        (const float*)d_in[12], (float*)d_out);
}